// Round 1
// baseline (763.770 us; speedup 1.0000x reference)
//
#include <hip/hip_runtime.h>
#include <math.h>

#define NLVL 16
#define TSIZE (1u << 19)

struct ScalingsArg { float s[NLVL]; };

__global__ __launch_bounds__(256) void ngp_fused(
    const float* __restrict__ x,
    const float2* __restrict__ table,
    const float* __restrict__ w1,
    const float* __restrict__ w2,
    float* __restrict__ out,
    ScalingsArg sca, int npts)
{
    __shared__ float lw1[64 * 64];   // 16 KiB
    __shared__ float lw2[64 * 16];   // 4 KiB

    const int tid = threadIdx.x;
    #pragma unroll
    for (int i = 0; i < 16; ++i) lw1[tid + 256 * i] = w1[tid + 256 * i];
    #pragma unroll
    for (int i = 0; i < 4; ++i)  lw2[tid + 256 * i] = w2[tid + 256 * i];
    __syncthreads();

    const int gid = blockIdx.x * 256 + tid;
    if (gid >= npts) return;

    // ---- load the 6D input point (3 x float2, 8B-aligned since 24B stride) ----
    const float* xp = x + (size_t)gid * 6;
    float2 v0 = *reinterpret_cast<const float2*>(xp);
    float2 v1 = *reinterpret_cast<const float2*>(xp + 2);
    float2 v2 = *reinterpret_cast<const float2*>(xp + 4);
    float P[6] = { v0.x, v0.y, v1.x, v1.y, v2.x, v2.y };

    // ---- hash-grid encode: 2 points x 16 levels x 2 features ----
    float enc[64];
    #pragma unroll
    for (int p = 0; p < 2; ++p) {
        const float qx = P[p * 3 + 0], qy = P[p * 3 + 1], qz = P[p * 3 + 2];
        #pragma unroll
        for (int l = 0; l < NLVL; ++l) {
            const float s = sca.s[l];
            const float sx = qx * s, sy = qy * s, sz = qz * s;
            const float fx = floorf(sx), fy = floorf(sy), fz = floorf(sz);
            const float wx = sx - fx, wy = sy - fy, wz = sz - fz;
            const unsigned ixf = (unsigned)(int)fx;
            const unsigned iyf = (unsigned)(int)fy;
            const unsigned izf = (unsigned)(int)fz;
            const unsigned ixc = (unsigned)(int)ceilf(sx);
            const unsigned iyc = (unsigned)(int)ceilf(sy);
            const unsigned izc = (unsigned)(int)ceilf(sz);
            const unsigned hyf = iyf * 2654435761u, hyc = iyc * 2654435761u;
            const unsigned hzf = izf * 805459861u,  hzc = izc * 805459861u;
            const unsigned base = (unsigned)l * TSIZE;
            const unsigned m = TSIZE - 1u;
            // corner mask rows: 0:(c,c,c) 1:(c,f,c) 2:(f,f,c) 3:(f,c,c)
            //                   4:(c,c,f) 5:(c,f,f) 6:(f,f,f) 7:(f,c,f)
            const float2 f0 = table[((ixc ^ hyc ^ hzc) & m) + base];
            const float2 f1 = table[((ixc ^ hyf ^ hzc) & m) + base];
            const float2 f2 = table[((ixf ^ hyf ^ hzc) & m) + base];
            const float2 f3 = table[((ixf ^ hyc ^ hzc) & m) + base];
            const float2 f4 = table[((ixc ^ hyc ^ hzf) & m) + base];
            const float2 f5 = table[((ixc ^ hyf ^ hzf) & m) + base];
            const float2 f6 = table[((ixf ^ hyf ^ hzf) & m) + base];
            const float2 f7 = table[((ixf ^ hyc ^ hzf) & m) + base];
            const float cx = 1.f - wx, cy = 1.f - wy, cz = 1.f - wz;
            const float g03x = f0.x * wx + f3.x * cx, g03y = f0.y * wx + f3.y * cx;
            const float g12x = f1.x * wx + f2.x * cx, g12y = f1.y * wx + f2.y * cx;
            const float g56x = f5.x * wx + f6.x * cx, g56y = f5.y * wx + f6.y * cx;
            const float g47x = f4.x * wx + f7.x * cx, g47y = f4.y * wx + f7.y * cx;
            const float t0x = g03x * wy + g12x * cy, t0y = g03y * wy + g12y * cy;
            const float t1x = g47x * wy + g56x * cy, t1y = g47y * wy + g56y * cy;
            enc[p * 32 + l * 2 + 0] = t0x * wz + t1x * cz;
            enc[p * 32 + l * 2 + 1] = t0y * wz + t1y * cz;
        }
    }

    // ---- MLP: h = relu(enc @ w1) fused with out = h @ w2 ----
    float o[16];
    #pragma unroll
    for (int t = 0; t < 16; ++t) o[t] = 0.f;

    for (int jb = 0; jb < 64; jb += 8) {   // dynamic loop keeps code size down
        float acc[8];
        #pragma unroll
        for (int jj = 0; jj < 8; ++jj) acc[jj] = 0.f;
        #pragma unroll
        for (int k = 0; k < 64; ++k) {     // full unroll: enc[k] stays in VGPRs
            const float e = enc[k];
            const float4* wrow = reinterpret_cast<const float4*>(&lw1[k * 64 + jb]);
            const float4 wa = wrow[0], wb = wrow[1];
            acc[0] += e * wa.x; acc[1] += e * wa.y; acc[2] += e * wa.z; acc[3] += e * wa.w;
            acc[4] += e * wb.x; acc[5] += e * wb.y; acc[6] += e * wb.z; acc[7] += e * wb.w;
        }
        #pragma unroll
        for (int jj = 0; jj < 8; ++jj) {
            const float hv = fmaxf(acc[jj], 0.f);
            const float4* w2row = reinterpret_cast<const float4*>(&lw2[(jb + jj) * 16]);
            const float4 wa = w2row[0], wb = w2row[1], wc = w2row[2], wd = w2row[3];
            o[0]  += hv * wa.x; o[1]  += hv * wa.y; o[2]  += hv * wa.z; o[3]  += hv * wa.w;
            o[4]  += hv * wb.x; o[5]  += hv * wb.y; o[6]  += hv * wb.z; o[7]  += hv * wb.w;
            o[8]  += hv * wc.x; o[9]  += hv * wc.y; o[10] += hv * wc.z; o[11] += hv * wc.w;
            o[12] += hv * wd.x; o[13] += hv * wd.y; o[14] += hv * wd.z; o[15] += hv * wd.w;
        }
    }

    o[0] = expf(o[0] - 1.0f);

    float4* op = reinterpret_cast<float4*>(out + (size_t)gid * 16);
    op[0] = make_float4(o[0],  o[1],  o[2],  o[3]);
    op[1] = make_float4(o[4],  o[5],  o[6],  o[7]);
    op[2] = make_float4(o[8],  o[9],  o[10], o[11]);
    op[3] = make_float4(o[12], o[13], o[14], o[15]);
}

extern "C" void kernel_launch(void* const* d_in, const int* in_sizes, int n_in,
                              void* d_out, int out_size, void* d_ws, size_t ws_size,
                              hipStream_t stream) {
    const float*  x     = (const float*)d_in[0];
    const float2* table = (const float2*)d_in[1];
    const float*  w1    = (const float*)d_in[2];
    const float*  w2    = (const float*)d_in[3];
    float* out = (float*)d_out;
    const int npts = in_sizes[0] / 6;

    // Replicate numpy's SCALINGS bit-exactly (same glibc libm as numpy):
    // growth = exp((log(4096)-log(16))/15); s[i] = float(floor(16 * growth**i))
    ScalingsArg sca;
    const double growth = exp((log(4096.0) - log(16.0)) / 15.0);
    for (int i = 0; i < NLVL; ++i)
        sca.s[i] = (float)floor(16.0 * pow(growth, (double)i));

    const int blocks = (npts + 255) / 256;
    ngp_fused<<<blocks, 256, 0, stream>>>(x, table, w1, w2, out, sca, npts);
}